// Round 1
// baseline (972.936 us; speedup 1.0000x reference)
//
#include <hip/hip_runtime.h>

#define SQ   2048
#define DD   512
#define HH   8
#define DEP  64
#define BSZ  4
#define MROWS (BSZ*SQ)   // 8192

typedef __bf16 bf16x8 __attribute__((ext_vector_type(8)));
typedef float  f32x4  __attribute__((ext_vector_type(4)));

__device__ __forceinline__ unsigned short f2bf(float f) {
  unsigned int u = __float_as_uint(f);
  u += 0x7fffu + ((u >> 16) & 1u);     // RNE
  return (unsigned short)(u >> 16);
}

__device__ __forceinline__ void gload_lds16(const void* g, void* l) {
  __builtin_amdgcn_global_load_lds(
      (__attribute__((address_space(1))) void*)g,
      (__attribute__((address_space(3))) void*)l, 16, 0, 0);
}

// ---------------- convert x (f32 -> bf16), vectorized ----------------
__global__ __launch_bounds__(256) void convx_kernel(const float* __restrict__ x,
                                                    ushort* __restrict__ xb, int n4) {
  int i = blockIdx.x * blockDim.x + threadIdx.x;
  if (i >= n4) return;
  float4 v = ((const float4*)x)[i];
  ushort4 o;
  o.x = f2bf(v.x); o.y = f2bf(v.y); o.z = f2bf(v.z); o.w = f2bf(v.w);
  ((ushort4*)xb)[i] = o;
}

// ---------------- W [K,N] f32 -> Wt [N,K] bf16 ----------------
__global__ void transw_kernel(const float* __restrict__ W, ushort* __restrict__ Wt) {
  __shared__ float t[16][17];
  int tx = threadIdx.x, ty = threadIdx.y;
  int nb = blockIdx.x, kb = blockIdx.y;
  t[ty][tx] = W[(size_t)(kb*16 + ty)*DD + nb*16 + tx];
  __syncthreads();
  Wt[(size_t)(nb*16 + ty)*DD + kb*16 + tx] = f2bf(t[tx][ty]);
}

// ---------------- 128x128-tile bf16 MFMA GEMM  (M=8192, N=512, K=512) ----------
// A [M,K] bf16 row-major, Bt [N,K] bf16 row-major.
// mode 0: Q -> [B,H,S,64] bf16, (v+bias)*0.125
// mode 1: K -> [B,H,S,64] bf16, v+bias
// mode 2: V -> [B,H,64,S] bf16 (transposed), v+bias
// mode 3: f32 out [M,N] = v+bias
__global__ __launch_bounds__(256) void gemm128(const ushort* __restrict__ A,
                                               const ushort* __restrict__ Bt,
                                               const float* __restrict__ bias,
                                               ushort* __restrict__ out_bf,
                                               float* __restrict__ out_f32,
                                               int mode) {
  __shared__ ushort ldsA[128*32];
  __shared__ ushort ldsB[128*32];
  const int tid = threadIdx.x;
  const int w = tid >> 6, lane = tid & 63;
  const int g = lane >> 4, li = lane & 15;
  const int wr = w >> 1, wc = w & 1;
  const int bm = blockIdx.y, bn = blockIdx.x;
  const int lrow = lane >> 2;
  const int lcol = (lane & 3) * 8;

  f32x4 acc[4][4];
#pragma unroll
  for (int mi = 0; mi < 4; ++mi)
#pragma unroll
    for (int ni = 0; ni < 4; ++ni) acc[mi][ni] = (f32x4){0.f,0.f,0.f,0.f};

  for (int kt = 0; kt < 16; ++kt) {
#pragma unroll
    for (int half = 0; half < 2; ++half) {
      int rb = w*32 + half*16;
      gload_lds16(A  + (size_t)(bm*128 + rb + lrow)*DD + kt*32 + lcol, &ldsA[rb*32]);
      gload_lds16(Bt + (size_t)(bn*128 + rb + lrow)*DD + kt*32 + lcol, &ldsB[rb*32]);
    }
    asm volatile("s_waitcnt vmcnt(0)" ::: "memory");
    __syncthreads();

    bf16x8 aF[4], bF[4];
#pragma unroll
    for (int mi = 0; mi < 4; ++mi)
      aF[mi] = *(const bf16x8*)&ldsA[(wr*64 + mi*16 + li)*32 + g*8];
#pragma unroll
    for (int ni = 0; ni < 4; ++ni)
      bF[ni] = *(const bf16x8*)&ldsB[(wc*64 + ni*16 + li)*32 + g*8];
#pragma unroll
    for (int mi = 0; mi < 4; ++mi)
#pragma unroll
      for (int ni = 0; ni < 4; ++ni)
        acc[mi][ni] = __builtin_amdgcn_mfma_f32_16x16x32_bf16(aF[mi], bF[ni], acc[mi][ni], 0, 0, 0);
    __syncthreads();
  }

  float bv[4];
#pragma unroll
  for (int ni = 0; ni < 4; ++ni) bv[ni] = bias[bn*128 + wc*64 + ni*16 + li];

#pragma unroll
  for (int mi = 0; mi < 4; ++mi) {
#pragma unroll
    for (int ni = 0; ni < 4; ++ni) {
      const int colg = bn*128 + wc*64 + ni*16 + li;
#pragma unroll
      for (int r = 0; r < 4; ++r) {
        const int rowg = bm*128 + wr*64 + mi*16 + g*4 + r;
        float v = acc[mi][ni][r] + bv[ni];
        if (mode == 3) {
          out_f32[(size_t)rowg*DD + colg] = v;
        } else {
          const int b = rowg >> 11, s = rowg & 2047;
          const int h = colg >> 6,  d = colg & 63;
          if (mode == 0) {
            out_bf[(((size_t)(b*HH + h)*SQ) + s)*DEP + d] = f2bf(v * 0.125f);
          } else if (mode == 1) {
            out_bf[(((size_t)(b*HH + h)*SQ) + s)*DEP + d] = f2bf(v);
          } else {
            out_bf[(((size_t)(b*HH + h)*DEP) + d)*SQ + s] = f2bf(v);
          }
        }
      }
    }
  }
}

// ---------------- fused attention -------------------------------------
// grid (32 qtiles, 32 bh), 256 threads = 4 waves; wave owns 16 q-rows.
// Pass1: online row max/sum.  Pass2: recompute S, write attn (f32),
// repack P->bf16 via wave-private LDS, accumulate ctx = P@V.
__global__ __launch_bounds__(256) void attn_fused(const ushort* __restrict__ qws,
                                                  const ushort* __restrict__ kws,
                                                  const ushort* __restrict__ vtws,
                                                  float* __restrict__ attn,
                                                  ushort* __restrict__ ctxws) {
  const int qt = blockIdx.x;
  const int bh = blockIdx.y;
  const int tid = threadIdx.x;
  const int w = tid >> 6, lane = tid & 63;
  const int g = lane >> 4, li = lane & 15;
  const int qrow0 = qt*64 + w*16;

  const ushort* qp = qws  + ((size_t)bh*SQ + qrow0)*DEP;
  const ushort* kp = kws  + (size_t)bh*SQ*DEP;
  const ushort* vp = vtws + (size_t)bh*DEP*SQ;

  __shared__ ushort plds[4][16][72];   // per-wave P tile, padded rows (144B)

  const bf16x8 qf0 = *(const bf16x8*)(qp + li*DEP + g*8);
  const bf16x8 qf1 = *(const bf16x8*)(qp + li*DEP + 32 + g*8);

  float m[4], l[4];
#pragma unroll
  for (int r = 0; r < 4; ++r) { m[r] = -1e30f; l[r] = 0.f; }

  // ---- pass 1: running max / sumexp ----
  for (int kt = 0; kt < 32; ++kt) {
    f32x4 acc[4];
#pragma unroll
    for (int ni = 0; ni < 4; ++ni) acc[ni] = (f32x4){0.f,0.f,0.f,0.f};
#pragma unroll
    for (int ni = 0; ni < 4; ++ni) {
      bf16x8 b0 = *(const bf16x8*)(kp + (size_t)(kt*64 + ni*16 + li)*DEP + g*8);
      acc[ni] = __builtin_amdgcn_mfma_f32_16x16x32_bf16(qf0, b0, acc[ni], 0, 0, 0);
    }
#pragma unroll
    for (int ni = 0; ni < 4; ++ni) {
      bf16x8 b1 = *(const bf16x8*)(kp + (size_t)(kt*64 + ni*16 + li)*DEP + 32 + g*8);
      acc[ni] = __builtin_amdgcn_mfma_f32_16x16x32_bf16(qf1, b1, acc[ni], 0, 0, 0);
    }
#pragma unroll
    for (int r = 0; r < 4; ++r) {
      float mx = fmaxf(fmaxf(acc[0][r], acc[1][r]), fmaxf(acc[2][r], acc[3][r]));
      mx = fmaxf(mx, __shfl_xor(mx, 1));
      mx = fmaxf(mx, __shfl_xor(mx, 2));
      mx = fmaxf(mx, __shfl_xor(mx, 4));
      mx = fmaxf(mx, __shfl_xor(mx, 8));
      float nm = fmaxf(m[r], mx);
      float corr = __expf(m[r] - nm);
      float se = __expf(acc[0][r]-nm) + __expf(acc[1][r]-nm)
               + __expf(acc[2][r]-nm) + __expf(acc[3][r]-nm);
      se += __shfl_xor(se, 1);
      se += __shfl_xor(se, 2);
      se += __shfl_xor(se, 4);
      se += __shfl_xor(se, 8);
      l[r] = l[r]*corr + se;
      m[r] = nm;
    }
  }
  float rinv[4];
#pragma unroll
  for (int r = 0; r < 4; ++r) rinv[r] = 1.0f / l[r];

  // ---- pass 2: recompute S, write attn, accumulate ctx ----
  f32x4 ctx[4];
#pragma unroll
  for (int ni = 0; ni < 4; ++ni) ctx[ni] = (f32x4){0.f,0.f,0.f,0.f};
  float* aout = attn + ((size_t)bh*SQ + qrow0)*SQ;

  for (int kt = 0; kt < 32; ++kt) {
    f32x4 acc[4];
#pragma unroll
    for (int ni = 0; ni < 4; ++ni) acc[ni] = (f32x4){0.f,0.f,0.f,0.f};
#pragma unroll
    for (int ni = 0; ni < 4; ++ni) {
      bf16x8 b0 = *(const bf16x8*)(kp + (size_t)(kt*64 + ni*16 + li)*DEP + g*8);
      acc[ni] = __builtin_amdgcn_mfma_f32_16x16x32_bf16(qf0, b0, acc[ni], 0, 0, 0);
    }
#pragma unroll
    for (int ni = 0; ni < 4; ++ni) {
      bf16x8 b1 = *(const bf16x8*)(kp + (size_t)(kt*64 + ni*16 + li)*DEP + 32 + g*8);
      acc[ni] = __builtin_amdgcn_mfma_f32_16x16x32_bf16(qf1, b1, acc[ni], 0, 0, 0);
    }
#pragma unroll
    for (int ni = 0; ni < 4; ++ni) {
#pragma unroll
      for (int r = 0; r < 4; ++r) {
        float p = __expf(acc[ni][r] - m[r]) * rinv[r];
        aout[(size_t)(g*4 + r)*SQ + kt*64 + ni*16 + li] = p;
        plds[w][g*4 + r][ni*16 + li] = f2bf(p);
      }
    }
    asm volatile("s_waitcnt lgkmcnt(0)" ::: "memory");
    __builtin_amdgcn_sched_barrier(0);
#pragma unroll
    for (int kk = 0; kk < 2; ++kk) {
      bf16x8 pf = *(const bf16x8*)&plds[w][li][kk*32 + g*8];
#pragma unroll
      for (int ni = 0; ni < 4; ++ni) {
        bf16x8 vf = *(const bf16x8*)(vp + (size_t)(ni*16 + li)*SQ + kt*64 + kk*32 + g*8);
        ctx[ni] = __builtin_amdgcn_mfma_f32_16x16x32_bf16(pf, vf, ctx[ni], 0, 0, 0);
      }
    }
    asm volatile("s_waitcnt lgkmcnt(0)" ::: "memory");
    __builtin_amdgcn_sched_barrier(0);
  }

  const int b = bh >> 3, h = bh & 7;
#pragma unroll
  for (int ni = 0; ni < 4; ++ni)
#pragma unroll
    for (int r = 0; r < 4; ++r)
      ctxws[((size_t)(b*SQ + qrow0 + g*4 + r))*DD + h*DEP + ni*16 + li] = f2bf(ctx[ni][r]);
}

// ---------------- launch ------------------------------------------------
extern "C" void kernel_launch(void* const* d_in, const int* in_sizes, int n_in,
                              void* d_out, int out_size, void* d_ws, size_t ws_size,
                              hipStream_t stream) {
  const float* x  = (const float*)d_in[0];
  const float* Wq = (const float*)d_in[1];
  const float* bq = (const float*)d_in[2];
  const float* Wk = (const float*)d_in[3];
  const float* bk = (const float*)d_in[4];
  const float* Wv = (const float*)d_in[5];
  const float* bv = (const float*)d_in[6];
  const float* Wo = (const float*)d_in[7];
  const float* bo = (const float*)d_in[8];

  float* out  = (float*)d_out;
  float* attn = out + (size_t)MROWS*DD;

  char* ws = (char*)d_ws;
  ushort* xb    = (ushort*)(ws);                               // 8 MB
  ushort* wqt   = (ushort*)(ws + 8388608);                     // 4 x 512 KB
  ushort* wkt   = wqt + 262144;
  ushort* wvt   = wkt + 262144;
  ushort* wot   = wvt + 262144;
  ushort* qws   = (ushort*)(ws + 8388608 + 4*524288);          // 8 MB
  ushort* kws   = qws  + 4194304;                              // 8 MB
  ushort* vtws  = kws  + 4194304;                              // 8 MB
  ushort* ctxws = vtws + 4194304;                              // 8 MB

  convx_kernel<<<4096, 256, 0, stream>>>(x, xb, 1048576);
  {
    dim3 tb(16, 16), tg(32, 32);
    transw_kernel<<<tg, tb, 0, stream>>>(Wq, wqt);
    transw_kernel<<<tg, tb, 0, stream>>>(Wk, wkt);
    transw_kernel<<<tg, tb, 0, stream>>>(Wv, wvt);
    transw_kernel<<<tg, tb, 0, stream>>>(Wo, wot);
  }
  dim3 gg(4, 64);
  gemm128<<<gg, 256, 0, stream>>>(xb, wqt, bq, qws,  nullptr, 0);
  gemm128<<<gg, 256, 0, stream>>>(xb, wkt, bk, kws,  nullptr, 1);
  gemm128<<<gg, 256, 0, stream>>>(xb, wvt, bv, vtws, nullptr, 2);

  dim3 ag(32, 32);
  attn_fused<<<ag, 256, 0, stream>>>(qws, kws, vtws, attn, ctxws);

  gemm128<<<gg, 256, 0, stream>>>(ctxws, wot, bo, nullptr, out, 3);
}